// Round 1
// 145.538 us; speedup vs baseline: 1.1848x; 1.1848x over previous
//
#include <hip/hip_runtime.h>
#include <math.h>

// Problem: E=8, B=4096, D=128, N=8192.
// out[b,n] = softmax_n( x[b,:] @ W[e(b)] + bias[e(b)] ) for the (unique) bin e(b), else 0.
//
// Strategy this round: replace fp32 VALU GEMM (MfmaUtil=0, 37% of fp32 peak) with
// bf16 MFMA via 3-term split:  x*W ~= x_hi*W_hi + x_lo*W_hi + x_hi*W_lo
// expressed as one K=384 augmented GEMM. Residual error ~2^-16 relative -> absmax stays ~1e-5.
// Pipeline: bin -> convert (split + transpose active experts' W to [n][k] bf16) ->
//           gemm_mfma (16x16x32 bf16, 128x128 tile) -> softmax (unchanged).
// Fallback to the previous fp32 GEMM if ws_size < ~34 MB needed for bf16 planes.

#define B_ROWS 4096
#define D_DIM  128
#define N_DIM  8192
#define E_NUM  8

typedef __attribute__((ext_vector_type(8))) __bf16 bf16x8;
typedef __attribute__((ext_vector_type(4))) float  f32x4;

__device__ __forceinline__ unsigned short f2bf(float f) {
    unsigned int u = __float_as_uint(f);
    unsigned int r = u + 0x7FFFu + ((u >> 16) & 1u);   // round-to-nearest-even
    return (unsigned short)(r >> 16);
}
__device__ __forceinline__ float bf2f(unsigned short h) {
    return __uint_as_float(((unsigned int)h) << 16);
}

// ws int layout:
//   [0]         n_tiles
//   [8..79]     tile_e
//   [96..167]   tile_start
//   [184..255]  tile_cnt
//   [448..455]  per-expert counts (for convert active check)
//   [512..4607] sorted row indices (grouped by expert)
// byte 65536+ : x_hi (1MB) | x_lo (1MB) | W_hi (16MB) | W_lo (16MB)   [bf16]

__global__ __launch_bounds__(1024)
void bin_kernel(const float* __restrict__ x,
                const float* __restrict__ tlo,
                const float* __restrict__ thi,
                int* __restrict__ ws_i, int m_tile) {
    __shared__ int cnt_s[E_NUM];
    __shared__ int off_s[E_NUM];
    __shared__ int cur_s[E_NUM];
    __shared__ int e_row[B_ROWS];

    int tid = threadIdx.x;
    if (tid < E_NUM) cnt_s[tid] = 0;
    __syncthreads();

    for (int r = tid; r < B_ROWS; r += 1024) {
        float th = x[(size_t)r * D_DIM];   // x[r, 0]
        int e = -1;
        #pragma unroll
        for (int i = 0; i < E_NUM; ++i) {
            if (e < 0 && th > tlo[i] && th <= thi[i]) e = i;  // first match
        }
        e_row[r] = e;
        if (e >= 0) atomicAdd(&cnt_s[e], 1);
    }
    __syncthreads();

    if (tid == 0) {
        int off = 0;
        for (int e = 0; e < E_NUM; ++e) {
            ws_i[448 + e] = cnt_s[e];
            off_s[e] = off;
            cur_s[e] = off;
            off += cnt_s[e];
        }
        int nt = 0;
        for (int e = 0; e < E_NUM; ++e) {
            int c = cnt_s[e];
            int s = off_s[e];
            for (int t0 = 0; t0 < c && nt < 72; t0 += m_tile) {
                ws_i[8 + nt]   = e;
                ws_i[96 + nt]  = s + t0;
                ws_i[184 + nt] = (c - t0 < m_tile) ? (c - t0) : m_tile;
                ++nt;
            }
        }
        ws_i[0] = nt;
    }
    __syncthreads();

    for (int r = tid; r < B_ROWS; r += 1024) {
        int e = e_row[r];
        if (e >= 0) {
            int p = atomicAdd(&cur_s[e], 1);
            ws_i[512 + p] = r;
        }
    }
}

// Split x and active experts' W into bf16 hi/lo. W output layout is TRANSPOSED to
// [e][n][k] (k contiguous) so MFMA B-fragments are 16B contiguous loads.
__global__ __launch_bounds__(256)
void convert_kernel(const float* __restrict__ x, const float* __restrict__ W,
                    const int* __restrict__ ws_i,
                    unsigned short* __restrict__ xh, unsigned short* __restrict__ xl,
                    unsigned short* __restrict__ wh, unsigned short* __restrict__ wl) {
    int bid = blockIdx.x;
    int t = threadIdx.x;
    if (bid < 1024) {
        int e = bid >> 7;                       // 8 experts x 128 n-chunks of 64
        if (ws_i[448 + e] == 0) return;         // expert inactive -> skip
        int n0 = (bid & 127) * 64;
        __shared__ __align__(16) unsigned short hi_s[64][136];  // stride 272B = 17*16
        __shared__ __align__(16) unsigned short lo_s[64][136];
        const float* Wp = W + (size_t)e * D_DIM * N_DIM + n0;
        #pragma unroll
        for (int i = 0; i < 8; ++i) {
            int idx = i * 256 + t;              // 2048 float4 = 128 d-rows x 16
            int d  = idx >> 4;
            int j4 = idx & 15;
            float4 v = *(const float4*)(Wp + (size_t)d * N_DIM + j4 * 4);
            float fv[4] = {v.x, v.y, v.z, v.w};
            #pragma unroll
            for (int c = 0; c < 4; ++c) {
                unsigned short h = f2bf(fv[c]);
                hi_s[j4 * 4 + c][d] = h;
                lo_s[j4 * 4 + c][d] = f2bf(fv[c] - bf2f(h));
            }
        }
        __syncthreads();
        unsigned short* whp = wh + ((size_t)e * N_DIM + n0) * D_DIM;
        unsigned short* wlp = wl + ((size_t)e * N_DIM + n0) * D_DIM;
        #pragma unroll
        for (int i = 0; i < 4; ++i) {
            int idx = i * 256 + t;              // 1024 16B-chunks = 64 n-rows x 16
            int nl = idx >> 4;
            int ck = idx & 15;
            *(uint4*)(whp + (size_t)nl * D_DIM + ck * 8) = *(const uint4*)(&hi_s[nl][ck * 8]);
            *(uint4*)(wlp + (size_t)nl * D_DIM + ck * 8) = *(const uint4*)(&lo_s[nl][ck * 8]);
        }
    } else {
        // x split: 16 blocks cover 4096*128 floats, layout unchanged (k contiguous)
        int base = (bid - 1024) * 32768;
        for (int i = 0; i < 32; ++i) {
            int idx = base + (i * 256 + t) * 4;
            float4 v = *(const float4*)(x + idx);
            float fv[4] = {v.x, v.y, v.z, v.w};
            unsigned short hq[4], lq[4];
            #pragma unroll
            for (int c = 0; c < 4; ++c) {
                hq[c] = f2bf(fv[c]);
                lq[c] = f2bf(fv[c] - bf2f(hq[c]));
            }
            *(uint2*)(xh + idx) = *(const uint2*)hq;
            *(uint2*)(xl + idx) = *(const uint2*)lq;
        }
    }
}

// MFMA GEMM: block = 128 rows x 128 cols, 4 waves in 2x2 (each wave 64x64).
// K=384 augmented loop: t=0..3: x_hi*W_hi, t=4..7: x_lo*W_hi, t=8..11: x_hi*W_lo.
// A (both x planes) staged once in 64KB XOR-swizzled LDS; B streamed global->VGPR.
__global__ __launch_bounds__(256)
void gemm_mfma(const unsigned short* __restrict__ xh, const unsigned short* __restrict__ xl,
               const unsigned short* __restrict__ wh, const unsigned short* __restrict__ wl,
               const float* __restrict__ bias, const int* __restrict__ ws_i,
               float* __restrict__ out) {
    int bt = blockIdx.y;
    if (bt >= ws_i[0]) return;
    int e   = ws_i[8 + bt];
    int seg = ws_i[96 + bt];
    int cnt = ws_i[184 + bt];
    const int* sorted = ws_i + 512;

    __shared__ __align__(16) unsigned short a_s[2][128 * 128];  // exactly 64 KB

    int tid = threadIdx.x;
    // stage gathered x_hi/x_lo rows, XOR-swizzled (G4): byte ^= (row&7)<<4
    #pragma unroll
    for (int i = 0; i < 8; ++i) {
        int idx = i * 256 + tid;     // 2048 chunks = 128 rows x 16 x 16B
        int row = idx >> 4;
        int ck  = idx & 15;
        uint4 vh = make_uint4(0, 0, 0, 0), vl = make_uint4(0, 0, 0, 0);
        if (row < cnt) {
            int r = sorted[seg + row];
            vh = *(const uint4*)(xh + (size_t)r * D_DIM + ck * 8);
            vl = *(const uint4*)(xl + (size_t)r * D_DIM + ck * 8);
        }
        int boff = row * 256 + ((ck * 16) ^ ((row & 7) << 4));
        *(uint4*)((char*)(&a_s[0][0]) + boff) = vh;
        *(uint4*)((char*)(&a_s[1][0]) + boff) = vl;
    }
    __syncthreads();   // only barrier: K-loop is barrier-free (A fully resident)

    int lane = tid & 63;
    int wave = tid >> 6;
    int wm = wave >> 1, wn = wave & 1;
    int l15 = lane & 15, q = lane >> 4;
    int colbase = blockIdx.x * 128 + wn * 64;

    const unsigned short* whp = wh + (size_t)e * N_DIM * D_DIM;
    const unsigned short* wlp = wl + (size_t)e * N_DIM * D_DIM;

    f32x4 acc[4][4];
    #pragma unroll
    for (int mi = 0; mi < 4; ++mi)
        #pragma unroll
        for (int nj = 0; nj < 4; ++nj)
            acc[mi][nj] = (f32x4){0.f, 0.f, 0.f, 0.f};

    #pragma unroll
    for (int t = 0; t < 12; ++t) {
        const int seg3  = t >> 2;
        const int plane = (seg3 == 1) ? 1 : 0;            // x_lo only in middle third
        const unsigned short* Bp = (seg3 == 2) ? wlp : whp;
        const int kk = (t & 3) * 32 + q * 8;              // element offset in K=128 plane

        bf16x8 bfr[4];
        #pragma unroll
        for (int nj = 0; nj < 4; ++nj)
            bfr[nj] = *(const bf16x8*)(Bp + (size_t)(colbase + nj * 16 + l15) * D_DIM + kk);

        bf16x8 afr[4];
        #pragma unroll
        for (int mi = 0; mi < 4; ++mi) {
            int row  = wm * 64 + mi * 16 + l15;
            int aoff = row * 256 + ((kk * 2) ^ ((row & 7) << 4));
            afr[mi] = *(const bf16x8*)((const char*)(&a_s[plane][0]) + aoff);
        }
        #pragma unroll
        for (int mi = 0; mi < 4; ++mi)
            #pragma unroll
            for (int nj = 0; nj < 4; ++nj)
                acc[mi][nj] = __builtin_amdgcn_mfma_f32_16x16x32_bf16(
                                  afr[mi], bfr[nj], acc[mi][nj], 0, 0, 0);
    }

    // epilogue: C/D layout col=lane&15, row=(lane>>4)*4+reg  [m89/m91 verified]
    const float* bp = bias + (size_t)e * N_DIM;
    float bvs[4];
    #pragma unroll
    for (int nj = 0; nj < 4; ++nj) bvs[nj] = bp[colbase + nj * 16 + l15];

    #pragma unroll
    for (int mi = 0; mi < 4; ++mi) {
        #pragma unroll
        for (int reg = 0; reg < 4; ++reg) {
            int m = wm * 64 + mi * 16 + q * 4 + reg;
            if (m < cnt) {
                int r = sorted[seg + m];
                float* op = out + (size_t)r * N_DIM + colbase;
                #pragma unroll
                for (int nj = 0; nj < 4; ++nj)
                    op[nj * 16 + l15] = acc[mi][nj][reg] + bvs[nj];
            }
        }
    }
}

// ---------------- fallback fp32 GEMM (previous kernel, sorted offset updated) ---------------

__device__ __forceinline__ void fma4(float4& ac, float xs, const float4& wv) {
    ac.x = fmaf(xs, wv.x, ac.x);
    ac.y = fmaf(xs, wv.y, ac.y);
    ac.z = fmaf(xs, wv.z, ac.z);
    ac.w = fmaf(xs, wv.w, ac.w);
}

__global__ __launch_bounds__(256)
void gemm_kernel(const float* __restrict__ x,
                 const float* __restrict__ W,
                 const float* __restrict__ bias,
                 const int* __restrict__ ws_i,
                 float* __restrict__ out) {
    int bt = blockIdx.y;
    if (bt >= ws_i[0]) return;
    int e   = ws_i[8 + bt];
    int seg = ws_i[96 + bt];
    int cnt = ws_i[184 + bt];
    const int* sorted = ws_i + 512;

    __shared__ float x_s[64][D_DIM];
    __shared__ int   rows_s[64];

    int tid = threadIdx.x;
    if (tid < 64) rows_s[tid] = (tid < cnt) ? sorted[seg + tid] : -1;
    __syncthreads();

    #pragma unroll
    for (int c = 0; c < 8; ++c) {
        int idx = c * 256 + tid;
        int i = idx >> 5;
        int k4 = idx & 31;
        int r = rows_s[i];
        float4 v;
        if (r >= 0) v = *(const float4*)(x + (size_t)r * D_DIM + k4 * 4);
        else        v = make_float4(0.f, 0.f, 0.f, 0.f);
        *(float4*)(&x_s[i][k4 * 4]) = v;
    }
    __syncthreads();

    int nidx = tid & 63;
    int mg   = tid >> 6;
    int col  = blockIdx.x * 256 + nidx * 4;
    const float* Wp = W + ((size_t)e * D_DIM) * N_DIM + col;

    float4 acc[16];
    #pragma unroll
    for (int i = 0; i < 16; ++i) acc[i] = make_float4(0.f, 0.f, 0.f, 0.f);

    for (int k = 0; k < D_DIM; k += 4) {
        float4 w0 = *(const float4*)(Wp + (size_t)(k + 0) * N_DIM);
        float4 w1 = *(const float4*)(Wp + (size_t)(k + 1) * N_DIM);
        float4 w2 = *(const float4*)(Wp + (size_t)(k + 2) * N_DIM);
        float4 w3 = *(const float4*)(Wp + (size_t)(k + 3) * N_DIM);
        #pragma unroll
        for (int i = 0; i < 16; ++i) {
            float4 xv = *(const float4*)(&x_s[mg * 16 + i][k]);
            fma4(acc[i], xv.x, w0);
            fma4(acc[i], xv.y, w1);
            fma4(acc[i], xv.z, w2);
            fma4(acc[i], xv.w, w3);
        }
    }

    float4 bv = *(const float4*)(bias + (size_t)e * N_DIM + col);
    #pragma unroll
    for (int i = 0; i < 16; ++i) {
        int m = mg * 16 + i;
        if (m < cnt) {
            int r = rows_s[m];
            float4 o = acc[i];
            o.x += bv.x; o.y += bv.y; o.z += bv.z; o.w += bv.w;
            *(float4*)(out + (size_t)r * N_DIM + col) = o;
        }
    }
}

// ---------------- softmax (unchanged) ---------------

__global__ __launch_bounds__(256)
void softmax_kernel(const float* __restrict__ x,
                    const float* __restrict__ tlo,
                    const float* __restrict__ thi,
                    float* __restrict__ out) {
    int r = blockIdx.x;
    int tid = threadIdx.x;
    float th = x[(size_t)r * D_DIM];
    bool valid = false;
    #pragma unroll
    for (int i = 0; i < E_NUM; ++i) {
        if (th > tlo[i] && th <= thi[i]) valid = true;
    }
    float* row = out + (size_t)r * N_DIM;

    if (!valid) {
        float4 z = make_float4(0.f, 0.f, 0.f, 0.f);
        #pragma unroll
        for (int c = 0; c < 8; ++c)
            *(float4*)(row + c * 1024 + tid * 4) = z;
        return;
    }

    float4 v[8];
    float mx = -INFINITY;
    #pragma unroll
    for (int c = 0; c < 8; ++c) {
        v[c] = *(const float4*)(row + c * 1024 + tid * 4);
        mx = fmaxf(mx, fmaxf(fmaxf(v[c].x, v[c].y), fmaxf(v[c].z, v[c].w)));
    }

    __shared__ float red[8];
    #pragma unroll
    for (int o = 1; o < 64; o <<= 1) mx = fmaxf(mx, __shfl_xor(mx, o));
    if ((tid & 63) == 0) red[tid >> 6] = mx;
    __syncthreads();
    mx = fmaxf(fmaxf(red[0], red[1]), fmaxf(red[2], red[3]));

    float sum = 0.f;
    #pragma unroll
    for (int c = 0; c < 8; ++c) {
        v[c].x = expf(v[c].x - mx);
        v[c].y = expf(v[c].y - mx);
        v[c].z = expf(v[c].z - mx);
        v[c].w = expf(v[c].w - mx);
        sum += v[c].x + v[c].y + v[c].z + v[c].w;
    }
    #pragma unroll
    for (int o = 1; o < 64; o <<= 1) sum += __shfl_xor(sum, o);
    if ((tid & 63) == 0) red[4 + (tid >> 6)] = sum;
    __syncthreads();
    sum = red[4] + red[5] + red[6] + red[7];

    float inv = 1.0f / sum;
    #pragma unroll
    for (int c = 0; c < 8; ++c) {
        float4 o;
        o.x = v[c].x * inv; o.y = v[c].y * inv;
        o.z = v[c].z * inv; o.w = v[c].w * inv;
        *(float4*)(row + c * 1024 + tid * 4) = o;
    }
}

extern "C" void kernel_launch(void* const* d_in, const int* in_sizes, int n_in,
                              void* d_out, int out_size, void* d_ws, size_t ws_size,
                              hipStream_t stream) {
    const float* x   = (const float*)d_in[0];
    const float* W   = (const float*)d_in[1];
    const float* b   = (const float*)d_in[2];
    const float* tlo = (const float*)d_in[3];
    const float* thi = (const float*)d_in[4];
    float* out = (float*)d_out;
    int* ws_i = (int*)d_ws;

    const size_t meta = 65536;
    const size_t xsz = (size_t)B_ROWS * D_DIM;
    const size_t wsz = (size_t)E_NUM * N_DIM * D_DIM;
    unsigned short* xh = (unsigned short*)((char*)d_ws + meta);
    unsigned short* xl = xh + xsz;
    unsigned short* wh = xl + xsz;
    unsigned short* wl = wh + wsz;
    size_t need = meta + (2 * xsz + 2 * wsz) * sizeof(unsigned short);
    bool fast = (ws_size >= need);

    bin_kernel<<<1, 1024, 0, stream>>>(x, tlo, thi, ws_i, fast ? 128 : 64);
    if (fast) {
        convert_kernel<<<1040, 256, 0, stream>>>(x, W, ws_i, xh, xl, wh, wl);
        gemm_mfma<<<dim3(N_DIM / 128, 40), 256, 0, stream>>>(xh, xl, wh, wl, b, ws_i, out);
    } else {
        gemm_kernel<<<dim3(N_DIM / 256, 72), 256, 0, stream>>>(x, W, b, ws_i, out);
    }
    softmax_kernel<<<B_ROWS, 256, 0, stream>>>(x, tlo, thi, out);
}